// Round 2
// baseline (5389.251 us; speedup 1.0000x reference)
//
#include <hip/hip_runtime.h>
#include <hip/hip_bf16.h>
#include <stdint.h>

#define NB 65536      // B rows
#define ND 256        // D
#define NK 2048       // K
#define NL 4          // L

// ---------------- init: copy residual -> res (ws) ----------------
__global__ void k_init(const float4* __restrict__ src, float4* __restrict__ dst) {
    const int i = blockIdx.x * 256 + threadIdx.x;
    dst[i] = src[i];
}

// ---------------- e2: numpy-pairwise sum of emb^2 per row ----------------
// block: 64 threads handles 32 rows of the [L*K, D] codebook matrix
__global__ void k_e2(const float* __restrict__ cb, float* __restrict__ e2) {
    __shared__ float tile[32 * 260];
    const int rowbase = blockIdx.x * 32;
    const float4* cb4 = (const float4*)(cb + (size_t)rowbase * ND);
    for (int it = 0; it < 32; ++it) {
        float4 v = cb4[it * 64 + threadIdx.x];
        *(float4*)&tile[it * 260 + threadIdx.x * 4] = v;
    }
    __syncthreads();
    if (threadIdx.x < 32) {
        const float* a = &tile[threadIdx.x * 260];
        float halves[2];
        for (int h = 0; h < 2; ++h) {
            const float* p = a + h * 128;
            float r8[8];
            #pragma unroll
            for (int j = 0; j < 8; ++j) r8[j] = __fmul_rn(p[j], p[j]);
            for (int i = 8; i < 128; i += 8) {
                #pragma unroll
                for (int j = 0; j < 8; ++j) r8[j] = __fadd_rn(r8[j], __fmul_rn(p[i + j], p[i + j]));
            }
            halves[h] = __fadd_rn(__fadd_rn(__fadd_rn(r8[0], r8[1]), __fadd_rn(r8[2], r8[3])),
                                  __fadd_rn(__fadd_rn(r8[4], r8[5]), __fadd_rn(r8[6], r8[7])));
        }
        e2[rowbase + threadIdx.x] = __fadd_rn(halves[0], halves[1]);
    }
}

// ---------------- per-level fused score GEMM + argmin ----------------
// block: 512 threads, 128 rows, all K=2048; 64-k tiles x 64-d chunks; 4x4 micro-tile.
__global__ __launch_bounds__(512)
void k_level(const float* __restrict__ res,
             const float* __restrict__ emb,      // [K, D] this level
             const float* __restrict__ e2,       // [K]  this level
             int* __restrict__ idx_buf,
             float* __restrict__ codes,          // fp32 [B, L] (int values)
             int level)
{
    __shared__ float resT[ND * 128];   // swizzled transposed [d][r], 128 KB
    __shared__ float embT[64 * 64];    // swizzled transposed [dl][k], 16 KB
    __shared__ float x2s[128];

    const int tid = threadIdx.x;
    const int tx = tid & 15;           // k-group (4 ks)
    const int ty = tid >> 4;           // row-group (4 rows), 0..31
    const int rowbase = blockIdx.x * 128;

    // stage resT: lanes differ in r -> conflict-free LDS writes (banks fully spread)
    {
        const int r = tid & 127;
        const int dg = tid >> 7;       // 0..3
        const int g = r >> 2, e = r & 3;
        const float* rowp = res + (size_t)(rowbase + r) * ND;
        #pragma unroll 8
        for (int t = 0; t < 64; ++t) {
            const int d = dg + t * 4;
            resT[d * 128 + ((g ^ (d & 31)) << 2) + e] = rowp[d];
        }
    }
    __syncthreads();

    // x2 per row: numpy pairwise (n=256 -> 128+128, 8-accumulator tree), exact op order
    if (tid < 128) {
        const int r = tid;
        const int g = r >> 2, e = r & 3;
        float halves[2];
        for (int h = 0; h < 2; ++h) {
            float r8[8];
            #pragma unroll
            for (int j = 0; j < 8; ++j) {
                const int d = h * 128 + j;
                const float v = resT[d * 128 + ((g ^ (d & 31)) << 2) + e];
                r8[j] = __fmul_rn(v, v);
            }
            for (int i = 8; i < 128; i += 8) {
                #pragma unroll
                for (int j = 0; j < 8; ++j) {
                    const int d = h * 128 + i + j;
                    const float v = resT[d * 128 + ((g ^ (d & 31)) << 2) + e];
                    r8[j] = __fadd_rn(r8[j], __fmul_rn(v, v));
                }
            }
            halves[h] = __fadd_rn(__fadd_rn(__fadd_rn(r8[0], r8[1]), __fadd_rn(r8[2], r8[3])),
                                  __fadd_rn(__fadd_rn(r8[4], r8[5]), __fadd_rn(r8[6], r8[7])));
        }
        x2s[r] = __fadd_rn(halves[0], halves[1]);
    }
    // (first __syncthreads inside the k-tile loop orders x2s writes before reads)

    float best_s[4];
    int best_k[4];
    #pragma unroll
    for (int i = 0; i < 4; ++i) { best_s[i] = 1e30f; best_k[i] = 0; }

    #pragma unroll 1
    for (int kt = 0; kt < 32; ++kt) {
        const int k0 = kt * 64;
        float acc[16];
        #pragma unroll
        for (int i = 0; i < 16; ++i) acc[i] = 0.0f;

        #pragma unroll 1
        for (int dc = 0; dc < 4; ++dc) {
            __syncthreads();
            // stage embT chunk: k tile [k0,k0+64), d chunk [dc*64, dc*64+64)
            #pragma unroll
            for (int t = 0; t < 2; ++t) {
                const int fi = tid + t * 512;        // 0..1023
                const int k = fi >> 4;               // 16 float4 per k-row
                const int dq = fi & 15;
                const float4 v = *(const float4*)&emb[(size_t)(k0 + k) * ND + dc * 64 + dq * 4];
                const int g = k >> 2, e = k & 3;
                const float* vp = (const float*)&v;
                #pragma unroll
                for (int di = 0; di < 4; ++di) {
                    const int dl = dq * 4 + di;
                    embT[dl * 64 + ((g ^ (dl & 15)) << 2) + e] = vp[di];
                }
            }
            __syncthreads();

            const int dbase = dc * 64;
            // single-accumulator fp32 FMA chain over d ascending (BLAS sgemm order)
            #pragma unroll 16
            for (int dl = 0; dl < 64; ++dl) {
                const int d = dbase + dl;
                const float4 af = *(const float4*)&resT[d * 128 + ((ty ^ (d & 31)) << 2)];
                const float4 bf = *(const float4*)&embT[dl * 64 + ((tx ^ (dl & 15)) << 2)];
                acc[0]  = __fmaf_rn(af.x, bf.x, acc[0]);
                acc[1]  = __fmaf_rn(af.x, bf.y, acc[1]);
                acc[2]  = __fmaf_rn(af.x, bf.z, acc[2]);
                acc[3]  = __fmaf_rn(af.x, bf.w, acc[3]);
                acc[4]  = __fmaf_rn(af.y, bf.x, acc[4]);
                acc[5]  = __fmaf_rn(af.y, bf.y, acc[5]);
                acc[6]  = __fmaf_rn(af.y, bf.z, acc[6]);
                acc[7]  = __fmaf_rn(af.y, bf.w, acc[7]);
                acc[8]  = __fmaf_rn(af.z, bf.x, acc[8]);
                acc[9]  = __fmaf_rn(af.z, bf.y, acc[9]);
                acc[10] = __fmaf_rn(af.z, bf.z, acc[10]);
                acc[11] = __fmaf_rn(af.z, bf.w, acc[11]);
                acc[12] = __fmaf_rn(af.w, bf.x, acc[12]);
                acc[13] = __fmaf_rn(af.w, bf.y, acc[13]);
                acc[14] = __fmaf_rn(af.w, bf.z, acc[14]);
                acc[15] = __fmaf_rn(af.w, bf.w, acc[15]);
            }
        }

        // scores: s = fl( fl(x2 + e2) - fl(2*M) ), running first-index argmin
        float e2v[4];
        #pragma unroll
        for (int j = 0; j < 4; ++j) e2v[j] = e2[k0 + tx * 4 + j];
        #pragma unroll
        for (int i = 0; i < 4; ++i) {
            const float x2v = x2s[ty * 4 + i];
            #pragma unroll
            for (int j = 0; j < 4; ++j) {
                const float s = __fsub_rn(__fadd_rn(x2v, e2v[j]), __fmul_rn(2.0f, acc[i * 4 + j]));
                const int kk = k0 + tx * 4 + j;
                if (s < best_s[i]) { best_s[i] = s; best_k[i] = kk; }   // strict < keeps first k
            }
        }
    }

    // cross-thread merge per row, first-index tie-break (lexicographic on (s, k))
    __syncthreads();
    float* sArr = embT;                       // reuse: [128][16] floats
    int* kArr = (int*)(embT + 2048);          // [128][16] ints
    #pragma unroll
    for (int i = 0; i < 4; ++i) {
        const int r = ty * 4 + i;
        sArr[r * 16 + tx] = best_s[i];
        kArr[r * 16 + tx] = best_k[i];
    }
    __syncthreads();
    if (tid < 128) {
        const int r = tid;
        float bs = 1e30f; int bk = 0;
        #pragma unroll
        for (int t = 0; t < 16; ++t) {
            const float s = sArr[r * 16 + t];
            const int kk = kArr[r * 16 + t];
            if (s < bs || (s == bs && kk < bk)) { bs = s; bk = kk; }
        }
        const int row = rowbase + r;
        idx_buf[row] = bk;
        codes[(size_t)row * NL + level] = (float)bk;
    }
}

// ---------------- residual update: res -= emb[idx] ----------------
__global__ void k_update(float4* __restrict__ res, const float4* __restrict__ emb,
                         const int* __restrict__ idx_buf) {
    const int tid = blockIdx.x * 256 + threadIdx.x;
    const int r = tid >> 6, c = tid & 63;
    const int k = idx_buf[r];
    const float4 q = emb[(size_t)k * 64 + c];
    float4 v = res[tid];
    v.x = __fsub_rn(v.x, q.x);
    v.y = __fsub_rn(v.y, q.y);
    v.z = __fsub_rn(v.z, q.z);
    v.w = __fsub_rn(v.w, q.w);
    res[tid] = v;
}

// ---------------- finalize: quantized = residual - res_final (fp32) ----------------
__global__ void k_finalize(const float4* __restrict__ residual, const float4* __restrict__ res,
                           float4* __restrict__ outq) {
    const int i = blockIdx.x * 256 + threadIdx.x;
    const float4 a = residual[i];
    const float4 b = res[i];
    float4 o;
    o.x = __fsub_rn(a.x, b.x);
    o.y = __fsub_rn(a.y, b.y);
    o.z = __fsub_rn(a.z, b.z);
    o.w = __fsub_rn(a.w, b.w);
    outq[i] = o;
}

extern "C" void kernel_launch(void* const* d_in, const int* in_sizes, int n_in,
                              void* d_out, int out_size, void* d_ws, size_t ws_size,
                              hipStream_t stream) {
    const float* residual = (const float*)d_in[0];
    const float* codebooks = (const float*)d_in[1];

    float* res = (float*)d_ws;                       // [B, D] fp32, 64 MB
    float* e2 = res + (size_t)NB * ND;               // [L, K] fp32, 32 KB
    int* idx_buf = (int*)(e2 + NL * NK);             // [B] int32, 256 KB

    float* outq = (float*)d_out;                     // fp32 [B, D]
    float* codes = outq + (size_t)NB * ND;           // fp32 [B, L]

    const int n4blocks = NB * ND / 4 / 256;          // 16384

    k_init<<<n4blocks, 256, 0, stream>>>((const float4*)residual, (float4*)res);
    k_e2<<<NL * NK / 32, 64, 0, stream>>>(codebooks, e2);
    for (int l = 0; l < NL; ++l) {
        const float* emb = codebooks + (size_t)l * NK * ND;
        k_level<<<NB / 128, 512, 0, stream>>>(res, emb, e2 + (size_t)l * NK, idx_buf, codes, l);
        k_update<<<n4blocks, 256, 0, stream>>>((float4*)res, (const float4*)emb, idx_buf);
    }
    k_finalize<<<n4blocks, 256, 0, stream>>>((const float4*)residual, (const float4*)res,
                                             (float4*)d_out);
}

// Round 3
// 4165.574 us; speedup vs baseline: 1.2938x; 1.2938x over previous
//
#include <hip/hip_runtime.h>
#include <stdint.h>

#define NB 65536      // B rows
#define ND 256        // D
#define NK 2048       // K
#define NL 4          // L
#define THRM 0.0625f  // accept margin for MFMA screening (error bound ~1e-3)

typedef __attribute__((ext_vector_type(8))) short v8s;   // 8 bf16 (4 VGPR)
typedef __attribute__((ext_vector_type(4))) float v4f;   // MFMA acc

static __device__ __forceinline__ unsigned short bf16_rne_bits(float f) {
    unsigned int u = __float_as_uint(f);
    unsigned int r = (u + 0x7FFFu + ((u >> 16) & 1u)) >> 16;
    return (unsigned short)r;
}

static __device__ __forceinline__ void split8(const float* __restrict__ p, v8s& hi, v8s& lo) {
    #pragma unroll
    for (int c = 0; c < 8; ++c) {
        float x = p[c];
        unsigned short hb = bf16_rne_bits(x);
        float hf = __uint_as_float((unsigned int)hb << 16);
        unsigned short lb = bf16_rne_bits(__fsub_rn(x, hf));
        hi[c] = (short)hb;
        lo[c] = (short)lb;
    }
}

// ---------------- zero the per-level uncertain counters ----------------
__global__ void k_zero(int* __restrict__ cnt) {
    if (threadIdx.x < NL) cnt[threadIdx.x] = 0;
}

// ---------------- init: copy residual -> res (ws) ----------------
__global__ void k_init(const float4* __restrict__ src, float4* __restrict__ dst) {
    const int i = blockIdx.x * 256 + threadIdx.x;
    dst[i] = src[i];
}

// ---------------- e2: numpy-pairwise sum of emb^2 per row (validated r2) ----------------
__global__ void k_e2(const float* __restrict__ cb, float* __restrict__ e2) {
    __shared__ float tile[32 * 260];
    const int rowbase = blockIdx.x * 32;
    const float4* cb4 = (const float4*)(cb + (size_t)rowbase * ND);
    for (int it = 0; it < 32; ++it) {
        float4 v = cb4[it * 64 + threadIdx.x];
        *(float4*)&tile[it * 260 + threadIdx.x * 4] = v;
    }
    __syncthreads();
    if (threadIdx.x < 32) {
        const float* a = &tile[threadIdx.x * 260];
        float halves[2];
        for (int h = 0; h < 2; ++h) {
            const float* p = a + h * 128;
            float r8[8];
            #pragma unroll
            for (int j = 0; j < 8; ++j) r8[j] = __fmul_rn(p[j], p[j]);
            for (int i = 8; i < 128; i += 8) {
                #pragma unroll
                for (int j = 0; j < 8; ++j) r8[j] = __fadd_rn(r8[j], __fmul_rn(p[i + j], p[i + j]));
            }
            halves[h] = __fadd_rn(__fadd_rn(__fadd_rn(r8[0], r8[1]), __fadd_rn(r8[2], r8[3])),
                                  __fadd_rn(__fadd_rn(r8[4], r8[5]), __fadd_rn(r8[6], r8[7])));
        }
        e2[rowbase + threadIdx.x] = __fadd_rn(halves[0], halves[1]);
    }
}

// ---------------- split codebooks into fragment-major bf16 hi/lo ----------------
// layout (per level, 16B units): u = ((k>>4)*8 + (d>>5))*4*16 + ((d>>3)&3)*16 + (k&15)
__global__ void k_split_emb(const float* __restrict__ cb,
                            unsigned short* __restrict__ eh,
                            unsigned short* __restrict__ el) {
    const int f = blockIdx.x * 256 + threadIdx.x;     // 0 .. L*K*32
    const int g = f & 31;                             // d-group of 8
    const int k = (f >> 5) & (NK - 1);
    const int l = f >> 16;
    const float* p = cb + ((size_t)(l * NK + k) * ND + g * 8);
    float buf[8];
    *(float4*)&buf[0] = *(const float4*)p;
    *(float4*)&buf[4] = *(const float4*)(p + 4);
    v8s hi, lo;
    split8(buf, hi, lo);
    const size_t u = (size_t)l * 65536 + (size_t)(k >> 4) * 512 + (g >> 2) * 64 + (g & 3) * 16 + (k & 15);
    *(v8s*)(eh + u * 8) = hi;
    *(v8s*)(el + u * 8) = lo;
}

// ---------------- pass A: MFMA screening GEMM + best/second argmin ----------------
// 512 blocks x 256 thr; wave w owns rows blk*128 + w*32 .. +32; all K=2048.
__global__ __launch_bounds__(256, 2)
void k_passA(const float* __restrict__ res,
             const unsigned short* __restrict__ eh,   // level fragment-major hi
             const unsigned short* __restrict__ el,   // level fragment-major lo
             const float* __restrict__ e2,            // level e2
             int* __restrict__ idx_buf,
             float* __restrict__ codes,
             int* __restrict__ ulist,
             int* __restrict__ cnt,
             int level)
{
    __shared__ unsigned short btile[2][8192];         // 2 x 16KB hi-tiles (32 k each)

    const int tid = threadIdx.x;
    const int w = tid >> 6;
    const int lane = tid & 63;
    const int kloc = lane & 15;
    const int quad = lane >> 4;
    const int rowbase = blockIdx.x * 128 + w * 32;

    // resident A fragments: hi/lo split of this wave's 32 rows
    v8s ah[2][8], al[2][8];
    #pragma unroll
    for (int m = 0; m < 2; ++m) {
        const float* rp = res + (size_t)(rowbase + m * 16 + kloc) * ND;
        #pragma unroll
        for (int dc = 0; dc < 8; ++dc) {
            float buf[8];
            *(float4*)&buf[0] = *(const float4*)(rp + dc * 32 + quad * 8);
            *(float4*)&buf[4] = *(const float4*)(rp + dc * 32 + quad * 8 + 4);
            split8(buf, ah[m][dc], al[m][dc]);
        }
    }

    // per-lane running best/second for 8 owned row-slots (m*4+reg), col-stripe kloc
    float b1[8], b2[8];
    int k1[8];
    #pragma unroll
    for (int s = 0; s < 8; ++s) { b1[s] = 1e30f; b2[s] = 1e30f; k1[s] = 0; }

    // staging prefetch regs: 16KB tile / 256 thr = 64B each (4 x 16B, 4KB apart)
    uint4 pf[4];
    {
        const uint4* src = (const uint4*)eh;          // kt = 0 tile
        #pragma unroll
        for (int i = 0; i < 4; ++i) pf[i] = src[i * 256 + tid];
    }

    #pragma unroll 1
    for (int kt = 0; kt < 64; ++kt) {
        const int buf = kt & 1;
        // commit prefetched tile to LDS
        {
            uint4* dst = (uint4*)&btile[buf][0];
            #pragma unroll
            for (int i = 0; i < 4; ++i) dst[i * 256 + tid] = pf[i];
        }
        __syncthreads();
        // prefetch next tile (overlaps with MFMA below)
        if (kt < 63) {
            const uint4* src = (const uint4*)(eh + (size_t)(kt + 1) * 8192);
            #pragma unroll
            for (int i = 0; i < 4; ++i) pf[i] = src[i * 256 + tid];
        }

        #pragma unroll
        for (int nt = 0; nt < 2; ++nt) {
            const int kglob = kt * 32 + nt * 16 + kloc;
            const float e2v = e2[kglob];
            // lo b-frags straight from L2 (fragment-major, coalesced 16B/lane)
            v8s blf[8];
            {
                const v8s* lp = (const v8s*)el + ((size_t)(2 * kt + nt) * 512 + quad * 16 + kloc);
                #pragma unroll
                for (int dc = 0; dc < 8; ++dc) blf[dc] = lp[dc * 64];
            }
            v4f acc0 = {0.f, 0.f, 0.f, 0.f};
            v4f acc1 = {0.f, 0.f, 0.f, 0.f};
            #pragma unroll
            for (int dc = 0; dc < 8; ++dc) {
                const v8s bh = *(const v8s*)&btile[buf][(((nt * 8 + dc) * 4 + quad) * 16 + kloc) * 8];
                acc0 = __builtin_amdgcn_mfma_f32_16x16x32_bf16(ah[0][dc], bh, acc0, 0, 0, 0);
                acc0 = __builtin_amdgcn_mfma_f32_16x16x32_bf16(al[0][dc], bh, acc0, 0, 0, 0);
                acc1 = __builtin_amdgcn_mfma_f32_16x16x32_bf16(ah[1][dc], bh, acc1, 0, 0, 0);
                acc1 = __builtin_amdgcn_mfma_f32_16x16x32_bf16(al[1][dc], bh, acc1, 0, 0, 0);
            }
            #pragma unroll
            for (int dc = 0; dc < 8; ++dc) {
                acc0 = __builtin_amdgcn_mfma_f32_16x16x32_bf16(ah[0][dc], blf[dc], acc0, 0, 0, 0);
                acc1 = __builtin_amdgcn_mfma_f32_16x16x32_bf16(ah[1][dc], blf[dc], acc1, 0, 0, 0);
            }
            // approx scores: s = e2 - 2*dot (x2 is row-constant, irrelevant for argmin/margin)
            #pragma unroll
            for (int reg = 0; reg < 4; ++reg) {
                float s0 = __fmaf_rn(-2.0f, acc0[reg], e2v);
                if (s0 < b1[reg])      { b2[reg] = b1[reg]; b1[reg] = s0; k1[reg] = kglob; }
                else if (s0 < b2[reg]) { b2[reg] = s0; }
                float s1 = __fmaf_rn(-2.0f, acc1[reg], e2v);
                if (s1 < b1[4 + reg])      { b2[4 + reg] = b1[4 + reg]; b1[4 + reg] = s1; k1[4 + reg] = kglob; }
                else if (s1 < b2[4 + reg]) { b2[4 + reg] = s1; }
            }
        }
        __syncthreads();   // all waves done reading btile[buf] before it is overwritten
    }

    // merge best/second across the 16 lanes of each quad-group (same rows, different cols)
    #pragma unroll
    for (int off = 1; off < 16; off <<= 1) {
        #pragma unroll
        for (int s = 0; s < 8; ++s) {
            float o1 = __shfl_xor(b1[s], off, 16);
            float o2 = __shfl_xor(b2[s], off, 16);
            int   ok = __shfl_xor(k1[s], off, 16);
            float n1 = fminf(b1[s], o1);
            float hi = fmaxf(b1[s], o1);
            float n2 = fminf(fminf(b2[s], o2), hi);
            int   nk = (o1 < b1[s]) ? ok : k1[s];
            b1[s] = n1; b2[s] = n2; k1[s] = nk;
        }
    }

    if (kloc == 0) {
        #pragma unroll
        for (int s = 0; s < 8; ++s) {
            const int m = s >> 2, reg = s & 3;
            const int row = rowbase + m * 16 + quad * 4 + reg;
            idx_buf[row] = k1[s];
            codes[(size_t)row * NL + level] = (float)k1[s];
            if (b2[s] - b1[s] <= THRM) {
                int p = atomicAdd(cnt, 1);
                ulist[p] = row;
            }
        }
    }
}

// ---------------- exact re-rank of uncertain rows (bit-exact vs validated r2 path) ----------------
__global__ __launch_bounds__(256, 2)
void k_rerank(const float* __restrict__ res,
              const float* __restrict__ emb,      // level [K, D] fp32
              const float* __restrict__ e2,       // level e2
              const int* __restrict__ ulist,
              const int* __restrict__ cnt,
              int* __restrict__ idx_buf,
              float* __restrict__ codes,
              int level)
{
    __shared__ float resL[16 * 256];   // 16KB
    __shared__ float x2s[16];
    __shared__ int   urows[16];
    __shared__ float sM[16 * 64];
    __shared__ int   kM[16 * 64];

    const int t = threadIdx.x;
    const int klocal = t & 63;
    const int rg = t >> 6;
    const int n = *cnt;

    for (int base = blockIdx.x * 16; base < n; base += gridDim.x * 16) {
        const int m = min(16, n - base);
        __syncthreads();
        if (t < 16) urows[t] = (t < m) ? ulist[base + t] : ulist[base];
        __syncthreads();
        #pragma unroll
        for (int i = 0; i < 4; ++i) {
            const int fi = t + 256 * i;
            const int r = fi >> 6, q = fi & 63;
            ((float4*)resL)[r * 64 + q] = ((const float4*)(res + (size_t)urows[r] * ND))[q];
        }
        __syncthreads();
        if (t < 16) {
            const float* a = &resL[t * 256];
            float halves[2];
            for (int h = 0; h < 2; ++h) {
                const float* p = a + h * 128;
                float r8[8];
                #pragma unroll
                for (int j = 0; j < 8; ++j) r8[j] = __fmul_rn(p[j], p[j]);
                for (int i = 8; i < 128; i += 8) {
                    #pragma unroll
                    for (int j = 0; j < 8; ++j) r8[j] = __fadd_rn(r8[j], __fmul_rn(p[i + j], p[i + j]));
                }
                halves[h] = __fadd_rn(__fadd_rn(__fadd_rn(r8[0], r8[1]), __fadd_rn(r8[2], r8[3])),
                                      __fadd_rn(__fadd_rn(r8[4], r8[5]), __fadd_rn(r8[6], r8[7])));
            }
            x2s[t] = __fadd_rn(halves[0], halves[1]);
        }
        __syncthreads();

        float bs[4];
        int bk[4];
        #pragma unroll
        for (int j = 0; j < 4; ++j) { bs[j] = 1e30f; bk[j] = 0; }

        #pragma unroll 1
        for (int kt = 0; kt < 32; ++kt) {
            const int k = kt * 64 + klocal;
            const float4* ep = (const float4*)(emb + (size_t)k * ND);
            const float e2k = e2[k];
            float d0 = 0.f, d1 = 0.f, d2 = 0.f, d3 = 0.f;
            const float* r0 = &resL[(rg + 0) * 256];
            const float* r1 = &resL[(rg + 4) * 256];
            const float* r2 = &resL[(rg + 8) * 256];
            const float* r3 = &resL[(rg + 12) * 256];
            #pragma unroll 8
            for (int q = 0; q < 64; ++q) {
                const float4 ev = ep[q];
                d0 = __fmaf_rn(ev.x, r0[q*4+0], d0); d0 = __fmaf_rn(ev.y, r0[q*4+1], d0);
                d0 = __fmaf_rn(ev.z, r0[q*4+2], d0); d0 = __fmaf_rn(ev.w, r0[q*4+3], d0);
                d1 = __fmaf_rn(ev.x, r1[q*4+0], d1); d1 = __fmaf_rn(ev.y, r1[q*4+1], d1);
                d1 = __fmaf_rn(ev.z, r1[q*4+2], d1); d1 = __fmaf_rn(ev.w, r1[q*4+3], d1);
                d2 = __fmaf_rn(ev.x, r2[q*4+0], d2); d2 = __fmaf_rn(ev.y, r2[q*4+1], d2);
                d2 = __fmaf_rn(ev.z, r2[q*4+2], d2); d2 = __fmaf_rn(ev.w, r2[q*4+3], d2);
                d3 = __fmaf_rn(ev.x, r3[q*4+0], d3); d3 = __fmaf_rn(ev.y, r3[q*4+1], d3);
                d3 = __fmaf_rn(ev.z, r3[q*4+2], d3); d3 = __fmaf_rn(ev.w, r3[q*4+3], d3);
            }
            float s;
            s = __fsub_rn(__fadd_rn(x2s[rg + 0], e2k), __fmul_rn(2.0f, d0));
            if (s < bs[0]) { bs[0] = s; bk[0] = k; }
            s = __fsub_rn(__fadd_rn(x2s[rg + 4], e2k), __fmul_rn(2.0f, d1));
            if (s < bs[1]) { bs[1] = s; bk[1] = k; }
            s = __fsub_rn(__fadd_rn(x2s[rg + 8], e2k), __fmul_rn(2.0f, d2));
            if (s < bs[2]) { bs[2] = s; bk[2] = k; }
            s = __fsub_rn(__fadd_rn(x2s[rg + 12], e2k), __fmul_rn(2.0f, d3));
            if (s < bs[3]) { bs[3] = s; bk[3] = k; }
        }
        #pragma unroll
        for (int j = 0; j < 4; ++j) {
            sM[(rg + 4 * j) * 64 + klocal] = bs[j];
            kM[(rg + 4 * j) * 64 + klocal] = bk[j];
        }
        __syncthreads();
        if (t < m) {
            float fb = 1e30f; int fk = 0;
            for (int i = 0; i < 64; ++i) {
                const float s = sM[t * 64 + i];
                const int kk = kM[t * 64 + i];
                if (s < fb || (s == fb && kk < fk)) { fb = s; fk = kk; }
            }
            const int row = urows[t];
            idx_buf[row] = fk;
            codes[(size_t)row * NL + level] = (float)fk;
        }
    }
}

// ---------------- residual update: res -= emb[idx] (exact fp32) ----------------
__global__ void k_update(float4* __restrict__ res, const float4* __restrict__ emb,
                         const int* __restrict__ idx_buf) {
    const int tid = blockIdx.x * 256 + threadIdx.x;
    const int r = tid >> 6, c = tid & 63;
    const int k = idx_buf[r];
    const float4 q = emb[(size_t)k * 64 + c];
    float4 v = res[tid];
    v.x = __fsub_rn(v.x, q.x);
    v.y = __fsub_rn(v.y, q.y);
    v.z = __fsub_rn(v.z, q.z);
    v.w = __fsub_rn(v.w, q.w);
    res[tid] = v;
}

// ---------------- finalize: quantized = residual - res_final (fp32) ----------------
__global__ void k_finalize(const float4* __restrict__ residual, const float4* __restrict__ res,
                           float4* __restrict__ outq) {
    const int i = blockIdx.x * 256 + threadIdx.x;
    const float4 a = residual[i];
    const float4 b = res[i];
    float4 o;
    o.x = __fsub_rn(a.x, b.x);
    o.y = __fsub_rn(a.y, b.y);
    o.z = __fsub_rn(a.z, b.z);
    o.w = __fsub_rn(a.w, b.w);
    outq[i] = o;
}

extern "C" void kernel_launch(void* const* d_in, const int* in_sizes, int n_in,
                              void* d_out, int out_size, void* d_ws, size_t ws_size,
                              hipStream_t stream) {
    const float* residual = (const float*)d_in[0];
    const float* codebooks = (const float*)d_in[1];

    float* res = (float*)d_ws;                                   // 64 MB
    float* e2 = res + (size_t)NB * ND;                           // 32 KB
    int* idx_buf = (int*)(e2 + NL * NK);                         // 256 KB
    int* ulist = idx_buf + NB;                                   // 256 KB
    int* cnt = ulist + NB;                                       // + pad
    unsigned short* embF_hi = (unsigned short*)(cnt + 64);       // 4 MB
    unsigned short* embF_lo = embF_hi + (size_t)NL * NK * ND;    // 4 MB

    float* codes = (float*)d_out + (size_t)NB * ND;              // fp32 [B, L]

    const int n4blocks = NB * ND / 4 / 256;                      // 16384

    k_zero<<<1, 64, 0, stream>>>(cnt);
    k_init<<<n4blocks, 256, 0, stream>>>((const float4*)residual, (float4*)res);
    k_e2<<<NL * NK / 32, 64, 0, stream>>>(codebooks, e2);
    k_split_emb<<<NL * NK * 32 / 256, 256, 0, stream>>>(codebooks, embF_hi, embF_lo);

    for (int l = 0; l < NL; ++l) {
        const float* emb = codebooks + (size_t)l * NK * ND;
        const unsigned short* eh = embF_hi + (size_t)l * NK * ND;
        const unsigned short* el = embF_lo + (size_t)l * NK * ND;
        const float* e2l = e2 + (size_t)l * NK;
        k_passA<<<NB / 128, 256, 0, stream>>>(res, eh, el, e2l, idx_buf,
                                              codes, ulist, cnt + l, l);
        k_rerank<<<256, 256, 0, stream>>>(res, emb, e2l, ulist, cnt + l,
                                          idx_buf, codes, l);
        k_update<<<n4blocks, 256, 0, stream>>>((float4*)res, (const float4*)emb, idx_buf);
    }
    k_finalize<<<n4blocks, 256, 0, stream>>>((const float4*)residual, (const float4*)res,
                                             (float4*)d_out);
}

// Round 4
// 1803.360 us; speedup vs baseline: 2.9884x; 2.3099x over previous
//
#include <hip/hip_runtime.h>
#include <stdint.h>

#define NB 65536      // B rows
#define ND 256        // D
#define NK 2048       // K
#define NL 4          // L
#define THRM 0.01f    // accept margin for MFMA screening (error bound ~8e-4)

typedef __attribute__((ext_vector_type(8))) short v8s;   // 8 bf16 (4 VGPR)
typedef __attribute__((ext_vector_type(4))) float v4f;   // MFMA acc
typedef unsigned long long ull;

static __device__ __forceinline__ unsigned short bf16_rne_bits(float f) {
    unsigned int u = __float_as_uint(f);
    unsigned int r = (u + 0x7FFFu + ((u >> 16) & 1u)) >> 16;
    return (unsigned short)r;
}

static __device__ __forceinline__ void split8(const float* __restrict__ p, v8s& hi, v8s& lo) {
    #pragma unroll
    for (int c = 0; c < 8; ++c) {
        float x = p[c];
        unsigned short hb = bf16_rne_bits(x);
        float hf = __uint_as_float((unsigned int)hb << 16);
        unsigned short lb = bf16_rne_bits(__fsub_rn(x, hf));
        hi[c] = (short)hb;
        lo[c] = (short)lb;
    }
}

// ---------------- zero the per-level uncertain counters ----------------
__global__ void k_zero(int* __restrict__ cnt) {
    if (threadIdx.x < NL) cnt[threadIdx.x] = 0;
}

// ---------------- init: copy residual -> res (ws) ----------------
__global__ void k_init(const float4* __restrict__ src, float4* __restrict__ dst) {
    const int i = blockIdx.x * 256 + threadIdx.x;
    dst[i] = src[i];
}

// ---------------- e2: numpy-pairwise sum of emb^2 per row (validated r2) ----------------
__global__ void k_e2(const float* __restrict__ cb, float* __restrict__ e2) {
    __shared__ float tile[32 * 260];
    const int rowbase = blockIdx.x * 32;
    const float4* cb4 = (const float4*)(cb + (size_t)rowbase * ND);
    for (int it = 0; it < 32; ++it) {
        float4 v = cb4[it * 64 + threadIdx.x];
        *(float4*)&tile[it * 260 + threadIdx.x * 4] = v;
    }
    __syncthreads();
    if (threadIdx.x < 32) {
        const float* a = &tile[threadIdx.x * 260];
        float halves[2];
        for (int h = 0; h < 2; ++h) {
            const float* p = a + h * 128;
            float r8[8];
            #pragma unroll
            for (int j = 0; j < 8; ++j) r8[j] = __fmul_rn(p[j], p[j]);
            for (int i = 8; i < 128; i += 8) {
                #pragma unroll
                for (int j = 0; j < 8; ++j) r8[j] = __fadd_rn(r8[j], __fmul_rn(p[i + j], p[i + j]));
            }
            halves[h] = __fadd_rn(__fadd_rn(__fadd_rn(r8[0], r8[1]), __fadd_rn(r8[2], r8[3])),
                                  __fadd_rn(__fadd_rn(r8[4], r8[5]), __fadd_rn(r8[6], r8[7])));
        }
        e2[rowbase + threadIdx.x] = __fadd_rn(halves[0], halves[1]);
    }
}

// ---------------- split codebooks into fragment-major bf16 hi/lo ----------------
__global__ void k_split_emb(const float* __restrict__ cb,
                            unsigned short* __restrict__ eh,
                            unsigned short* __restrict__ el) {
    const int f = blockIdx.x * 256 + threadIdx.x;     // 0 .. L*K*32
    const int g = f & 31;                             // d-group of 8
    const int k = (f >> 5) & (NK - 1);
    const int l = f >> 16;
    const float* p = cb + ((size_t)(l * NK + k) * ND + g * 8);
    float buf[8];
    *(float4*)&buf[0] = *(const float4*)p;
    *(float4*)&buf[4] = *(const float4*)(p + 4);
    v8s hi, lo;
    split8(buf, hi, lo);
    const size_t u = (size_t)l * 65536 + (size_t)(k >> 4) * 512 + (g >> 2) * 64 + (g & 3) * 16 + (k & 15);
    *(v8s*)(eh + u * 8) = hi;
    *(v8s*)(el + u * 8) = lo;
}

// ---------------- pass A: MFMA screening GEMM + best/second argmin ----------------
__global__ __launch_bounds__(256, 2)
void k_passA(const float* __restrict__ res,
             const unsigned short* __restrict__ eh,
             const unsigned short* __restrict__ el,
             const float* __restrict__ e2,
             int* __restrict__ idx_buf,
             float* __restrict__ codes,
             int* __restrict__ ulist,
             int* __restrict__ cnt,
             int level)
{
    __shared__ unsigned short btile[2][8192];         // 2 x 16KB hi-tiles (32 k each)

    const int tid = threadIdx.x;
    const int w = tid >> 6;
    const int lane = tid & 63;
    const int kloc = lane & 15;
    const int quad = lane >> 4;
    const int rowbase = blockIdx.x * 128 + w * 32;

    v8s ah[2][8], al[2][8];
    #pragma unroll
    for (int m = 0; m < 2; ++m) {
        const float* rp = res + (size_t)(rowbase + m * 16 + kloc) * ND;
        #pragma unroll
        for (int dc = 0; dc < 8; ++dc) {
            float buf[8];
            *(float4*)&buf[0] = *(const float4*)(rp + dc * 32 + quad * 8);
            *(float4*)&buf[4] = *(const float4*)(rp + dc * 32 + quad * 8 + 4);
            split8(buf, ah[m][dc], al[m][dc]);
        }
    }

    float b1[8], b2[8];
    int k1[8];
    #pragma unroll
    for (int s = 0; s < 8; ++s) { b1[s] = 1e30f; b2[s] = 1e30f; k1[s] = 0; }

    uint4 pf[4];
    {
        const uint4* src = (const uint4*)eh;
        #pragma unroll
        for (int i = 0; i < 4; ++i) pf[i] = src[i * 256 + tid];
    }

    #pragma unroll 1
    for (int kt = 0; kt < 64; ++kt) {
        const int buf = kt & 1;
        {
            uint4* dst = (uint4*)&btile[buf][0];
            #pragma unroll
            for (int i = 0; i < 4; ++i) dst[i * 256 + tid] = pf[i];
        }
        __syncthreads();
        if (kt < 63) {
            const uint4* src = (const uint4*)(eh + (size_t)(kt + 1) * 8192);
            #pragma unroll
            for (int i = 0; i < 4; ++i) pf[i] = src[i * 256 + tid];
        }

        #pragma unroll
        for (int nt = 0; nt < 2; ++nt) {
            const int kglob = kt * 32 + nt * 16 + kloc;
            const float e2v = e2[kglob];
            v8s blf[8];
            {
                const v8s* lp = (const v8s*)el + ((size_t)(2 * kt + nt) * 512 + quad * 16 + kloc);
                #pragma unroll
                for (int dc = 0; dc < 8; ++dc) blf[dc] = lp[dc * 64];
            }
            v4f acc0 = {0.f, 0.f, 0.f, 0.f};
            v4f acc1 = {0.f, 0.f, 0.f, 0.f};
            #pragma unroll
            for (int dc = 0; dc < 8; ++dc) {
                const v8s bh = *(const v8s*)&btile[buf][(((nt * 8 + dc) * 4 + quad) * 16 + kloc) * 8];
                acc0 = __builtin_amdgcn_mfma_f32_16x16x32_bf16(ah[0][dc], bh, acc0, 0, 0, 0);
                acc0 = __builtin_amdgcn_mfma_f32_16x16x32_bf16(al[0][dc], bh, acc0, 0, 0, 0);
                acc1 = __builtin_amdgcn_mfma_f32_16x16x32_bf16(ah[1][dc], bh, acc1, 0, 0, 0);
                acc1 = __builtin_amdgcn_mfma_f32_16x16x32_bf16(al[1][dc], bh, acc1, 0, 0, 0);
            }
            #pragma unroll
            for (int dc = 0; dc < 8; ++dc) {
                acc0 = __builtin_amdgcn_mfma_f32_16x16x32_bf16(ah[0][dc], blf[dc], acc0, 0, 0, 0);
                acc1 = __builtin_amdgcn_mfma_f32_16x16x32_bf16(ah[1][dc], blf[dc], acc1, 0, 0, 0);
            }
            #pragma unroll
            for (int reg = 0; reg < 4; ++reg) {
                float s0 = __fmaf_rn(-2.0f, acc0[reg], e2v);
                if (s0 < b1[reg])      { b2[reg] = b1[reg]; b1[reg] = s0; k1[reg] = kglob; }
                else if (s0 < b2[reg]) { b2[reg] = s0; }
                float s1 = __fmaf_rn(-2.0f, acc1[reg], e2v);
                if (s1 < b1[4 + reg])      { b2[4 + reg] = b1[4 + reg]; b1[4 + reg] = s1; k1[4 + reg] = kglob; }
                else if (s1 < b2[4 + reg]) { b2[4 + reg] = s1; }
            }
        }
        __syncthreads();
    }

    #pragma unroll
    for (int off = 1; off < 16; off <<= 1) {
        #pragma unroll
        for (int s = 0; s < 8; ++s) {
            float o1 = __shfl_xor(b1[s], off, 16);
            float o2 = __shfl_xor(b2[s], off, 16);
            int   ok = __shfl_xor(k1[s], off, 16);
            float n1 = fminf(b1[s], o1);
            float hi = fmaxf(b1[s], o1);
            float n2 = fminf(fminf(b2[s], o2), hi);
            int   nk = (o1 < b1[s]) ? ok : k1[s];
            b1[s] = n1; b2[s] = n2; k1[s] = nk;
        }
    }

    if (kloc == 0) {
        #pragma unroll
        for (int s = 0; s < 8; ++s) {
            const int m = s >> 2, reg = s & 3;
            const int row = rowbase + m * 16 + quad * 4 + reg;
            idx_buf[row] = k1[s];
            codes[(size_t)row * NL + level] = (float)k1[s];
            if (b2[s] - b1[s] <= THRM) {
                int p = atomicAdd(cnt, 1);
                ulist[p] = row;
            }
        }
    }
}

// ---------------- rerank stage 1: exact scores, K-split, coalesced LDS staging ----------------
// grid: 2048 blocks = 64 rowtile-slots x 32 k-slices; 256 thr.
// thread t: row = t&15 of the 16-row tile, kgroup = t>>4 (4 consecutive k).
__global__ __launch_bounds__(256)
void k_rr1(const float* __restrict__ res,
           const float* __restrict__ emb,      // level [K, D]
           const float* __restrict__ e2,       // level e2
           const int* __restrict__ ulist,
           const int* __restrict__ cnt,
           ull* __restrict__ partial)          // [(NB+16)][32] packed (s,k)
{
    __shared__ float embL[64 * 260];   // 66.6 KB, stride-260 pad (bank-spread)
    __shared__ float resL[16 * 260];   // 16.6 KB
    __shared__ float x2s[16];
    __shared__ int   urows[16];
    __shared__ ull   redM[16][17];

    const int t = threadIdx.x;
    const int ks = blockIdx.x & 31;
    const int rt0 = blockIdx.x >> 5;
    const int n = *cnt;
    const int nrt = (n + 15) >> 4;
    if (rt0 >= nrt) return;

    // stage emb k-slice once per block (coalesced; reused across rowtiles)
    #pragma unroll
    for (int i = 0; i < 16; ++i) {
        const int fi = t + 256 * i;
        const int r = fi >> 6, q = fi & 63;
        *(float4*)&embL[r * 260 + q * 4] = *(const float4*)&emb[(size_t)(ks * 64 + r) * ND + q * 4];
    }
    const int row = t & 15;
    const int kg = t >> 4;
    float e2r[4];
    #pragma unroll
    for (int j = 0; j < 4; ++j) e2r[j] = e2[ks * 64 + kg * 4 + j];

    for (int rt = rt0; rt < nrt; rt += 64) {
        __syncthreads();
        if (t < 16) {
            const int i = rt * 16 + t;
            urows[t] = ulist[(i < n) ? i : rt * 16];
        }
        __syncthreads();
        #pragma unroll
        for (int i = 0; i < 4; ++i) {
            const int fi = t + 256 * i;
            const int r = fi >> 6, q = fi & 63;
            *(float4*)&resL[r * 260 + q * 4] = *(const float4*)&res[(size_t)urows[r] * ND + q * 4];
        }
        __syncthreads();
        // x2: numpy pairwise 8-acc tree (validated order)
        if (t < 16) {
            const float* a = &resL[t * 260];
            float halves[2];
            for (int h = 0; h < 2; ++h) {
                const float* p = a + h * 128;
                float r8[8];
                #pragma unroll
                for (int j = 0; j < 8; ++j) r8[j] = __fmul_rn(p[j], p[j]);
                for (int i = 8; i < 128; i += 8) {
                    #pragma unroll
                    for (int j = 0; j < 8; ++j) r8[j] = __fadd_rn(r8[j], __fmul_rn(p[i + j], p[i + j]));
                }
                halves[h] = __fadd_rn(__fadd_rn(__fadd_rn(r8[0], r8[1]), __fadd_rn(r8[2], r8[3])),
                                      __fadd_rn(__fadd_rn(r8[4], r8[5]), __fadd_rn(r8[6], r8[7])));
            }
            x2s[t] = __fadd_rn(halves[0], halves[1]);
        }
        __syncthreads();

        // exact dots: single-accumulator ascending-d chain (validated order), 4 ks
        float d0 = 0.f, d1 = 0.f, d2 = 0.f, d3 = 0.f;
        const float* rp = &resL[row * 260];
        const float* ep = &embL[(kg * 4) * 260];
        #pragma unroll 8
        for (int q = 0; q < 64; ++q) {
            const float4 rv = *(const float4*)&rp[q * 4];
            const float4 e0 = *(const float4*)&ep[q * 4];
            const float4 e1 = *(const float4*)&ep[260 + q * 4];
            const float4 ee2 = *(const float4*)&ep[520 + q * 4];
            const float4 e3 = *(const float4*)&ep[780 + q * 4];
            d0 = __fmaf_rn(rv.x, e0.x, d0); d0 = __fmaf_rn(rv.y, e0.y, d0);
            d0 = __fmaf_rn(rv.z, e0.z, d0); d0 = __fmaf_rn(rv.w, e0.w, d0);
            d1 = __fmaf_rn(rv.x, e1.x, d1); d1 = __fmaf_rn(rv.y, e1.y, d1);
            d1 = __fmaf_rn(rv.z, e1.z, d1); d1 = __fmaf_rn(rv.w, e1.w, d1);
            d2 = __fmaf_rn(rv.x, ee2.x, d2); d2 = __fmaf_rn(rv.y, ee2.y, d2);
            d2 = __fmaf_rn(rv.z, ee2.z, d2); d2 = __fmaf_rn(rv.w, ee2.w, d2);
            d3 = __fmaf_rn(rv.x, e3.x, d3); d3 = __fmaf_rn(rv.y, e3.y, d3);
            d3 = __fmaf_rn(rv.z, e3.z, d3); d3 = __fmaf_rn(rv.w, e3.w, d3);
        }

        const float x2v = x2s[row];
        const int kb = ks * 64 + kg * 4;
        float s;
        ull best, u;
        s = __fsub_rn(__fadd_rn(x2v, e2r[0]), __fmul_rn(2.0f, d0));
        best = ((ull)__float_as_uint(s) << 32) | (ull)(kb + 0);
        s = __fsub_rn(__fadd_rn(x2v, e2r[1]), __fmul_rn(2.0f, d1));
        u = ((ull)__float_as_uint(s) << 32) | (ull)(kb + 1);
        if (u < best) best = u;
        s = __fsub_rn(__fadd_rn(x2v, e2r[2]), __fmul_rn(2.0f, d2));
        u = ((ull)__float_as_uint(s) << 32) | (ull)(kb + 2);
        if (u < best) best = u;
        s = __fsub_rn(__fadd_rn(x2v, e2r[3]), __fmul_rn(2.0f, d3));
        u = ((ull)__float_as_uint(s) << 32) | (ull)(kb + 3);
        if (u < best) best = u;

        redM[row][kg] = best;
        __syncthreads();
        if (t < 16) {
            ull b = redM[t][0];
            #pragma unroll
            for (int g = 1; g < 16; ++g) { const ull v = redM[t][g]; if (v < b) b = v; }
            partial[(size_t)(rt * 16 + t) * 32 + ks] = b;
        }
    }
}

// ---------------- rerank stage 2: reduce 32 k-slices per uncertain row ----------------
__global__ void k_rr2(const ull* __restrict__ partial,
                      const int* __restrict__ ulist,
                      const int* __restrict__ cnt,
                      int* __restrict__ idx_buf,
                      float* __restrict__ codes,
                      int level)
{
    const int n = *cnt;
    for (int i = blockIdx.x * 256 + threadIdx.x; i < n; i += gridDim.x * 256) {
        const ull* p = &partial[(size_t)i * 32];
        ull b = p[0];
        #pragma unroll
        for (int s2 = 1; s2 < 32; ++s2) { const ull v = p[s2]; if (v < b) b = v; }
        const int k = (int)(b & 0xffffffffull);
        const int row = ulist[i];
        idx_buf[row] = k;
        codes[(size_t)row * NL + level] = (float)k;
    }
}

// ---------------- residual update: res -= emb[idx] (exact fp32) ----------------
__global__ void k_update(float4* __restrict__ res, const float4* __restrict__ emb,
                         const int* __restrict__ idx_buf) {
    const int tid = blockIdx.x * 256 + threadIdx.x;
    const int r = tid >> 6, c = tid & 63;
    const int k = idx_buf[r];
    const float4 q = emb[(size_t)k * 64 + c];
    float4 v = res[tid];
    v.x = __fsub_rn(v.x, q.x);
    v.y = __fsub_rn(v.y, q.y);
    v.z = __fsub_rn(v.z, q.z);
    v.w = __fsub_rn(v.w, q.w);
    res[tid] = v;
}

// ---------------- finalize: quantized = residual - res_final (fp32) ----------------
__global__ void k_finalize(const float4* __restrict__ residual, const float4* __restrict__ res,
                           float4* __restrict__ outq) {
    const int i = blockIdx.x * 256 + threadIdx.x;
    const float4 a = residual[i];
    const float4 b = res[i];
    float4 o;
    o.x = __fsub_rn(a.x, b.x);
    o.y = __fsub_rn(a.y, b.y);
    o.z = __fsub_rn(a.z, b.z);
    o.w = __fsub_rn(a.w, b.w);
    outq[i] = o;
}

extern "C" void kernel_launch(void* const* d_in, const int* in_sizes, int n_in,
                              void* d_out, int out_size, void* d_ws, size_t ws_size,
                              hipStream_t stream) {
    const float* residual = (const float*)d_in[0];
    const float* codebooks = (const float*)d_in[1];

    float* res = (float*)d_ws;                                   // 64 MB
    ull* partial = (ull*)(res + (size_t)NB * ND);                // 16.8 MB (8-aligned)
    float* e2 = (float*)(partial + (size_t)(NB + 16) * 32);      // 32 KB
    int* idx_buf = (int*)(e2 + NL * NK);                         // 256 KB
    int* ulist = idx_buf + NB;                                   // 256 KB
    int* cnt = ulist + NB;                                       // + pad
    unsigned short* embF_hi = (unsigned short*)(cnt + 64);       // 4 MB
    unsigned short* embF_lo = embF_hi + (size_t)NL * NK * ND;    // 4 MB

    float* codes = (float*)d_out + (size_t)NB * ND;              // fp32 [B, L]

    const int n4blocks = NB * ND / 4 / 256;                      // 16384

    k_zero<<<1, 64, 0, stream>>>(cnt);
    k_init<<<n4blocks, 256, 0, stream>>>((const float4*)residual, (float4*)res);
    k_e2<<<NL * NK / 32, 64, 0, stream>>>(codebooks, e2);
    k_split_emb<<<NL * NK * 32 / 256, 256, 0, stream>>>(codebooks, embF_hi, embF_lo);

    for (int l = 0; l < NL; ++l) {
        const float* emb = codebooks + (size_t)l * NK * ND;
        const unsigned short* eh = embF_hi + (size_t)l * NK * ND;
        const unsigned short* el = embF_lo + (size_t)l * NK * ND;
        const float* e2l = e2 + (size_t)l * NK;
        k_passA<<<NB / 128, 256, 0, stream>>>(res, eh, el, e2l, idx_buf,
                                              codes, ulist, cnt + l, l);
        k_rr1<<<2048, 256, 0, stream>>>(res, emb, e2l, ulist, cnt + l, partial);
        k_rr2<<<64, 256, 0, stream>>>(partial, ulist, cnt + l, idx_buf, codes, l);
        k_update<<<n4blocks, 256, 0, stream>>>((float4*)res, (const float4*)emb, idx_buf);
    }
    k_finalize<<<n4blocks, 256, 0, stream>>>((const float4*)residual, (const float4*)res,
                                             (float4*)d_out);
}